// Round 6
// baseline (187.311 us; speedup 1.0000x reference)
//
#include <hip/hip_runtime.h>
#include <cfloat>
#include <math.h>

#define N_TOK 32768
#define DIM   256
#define MCODE 1024

typedef unsigned short u16;
typedef unsigned long long u64;
typedef __attribute__((ext_vector_type(8))) _Float16 h16x8;
typedef __attribute__((ext_vector_type(4))) float f32x4;

constexpr float DECAY_ = 0.999f;
constexpr float OMD_   = (float)(1.0 - 0.999);   // match jax double->f32 promotion
constexpr float EPS_   = 1e-5f;
constexpr float MEPS_  = (float)(1024 * 1e-5);   // M * EPS in double, then f32

// ---- workspace layout (float offsets) ----
// MUST stay <= 3,284,992 B (Round-1-proven ws_size bound).
constexpr int WS_EH   = 0;        // eh[1024*256] fp16 (linear) -> 131072 float slots
constexpr int WS_ESQ  = 262144;   // esq[1024]
constexpr int WS_CNTI = 263168;   // int counts[1024] (zeroed in setup)
constexpr int WS_BI   = 264192;   // int bi[32768]
constexpr int WS_LP   = 296960;   // loss partials[2048]
constexpr int WS_KEY  = 299008;   // u64 keys[32768] (8B-aligned)

// ---- output layout (float offsets) ----
constexpr int OUT_Q        = 0;
constexpr int OUT_COMMIT   = 8388608;
constexpr int OUT_CODEBOOK = 8388609;
constexpr int OUT_PERP     = 8388610;
constexpr int OUT_NE       = 8388611;
constexpr int OUT_NC       = 8650755;
constexpr int OUT_NW       = 8651779;

// monotone float->uint map: a<b  <=>  map(a)<map(b)  (finite floats)
static __device__ __forceinline__ unsigned fmap(float f) {
    unsigned u = __float_as_uint(f);
    return (u & 0x80000000u) ? ~u : (u | 0x80000000u);
}

// LINEAR fp16 pack — fully coalesced stream (2x float4 in, 1x short8 out per
// thread). R5-proven fast for setup. Scores gathers per-lane from the linear
// arrays directly into registers.
static __device__ __forceinline__ void pack8_lin(const float* __restrict__ src,
                                                 u16* __restrict__ dst,
                                                 size_t i8, float scale) {
    float4 v0 = *(const float4*)&src[i8];
    float4 v1 = *(const float4*)&src[i8 + 4];
    h16x8 hv;
    hv[0]=(_Float16)(v0.x*scale); hv[1]=(_Float16)(v0.y*scale);
    hv[2]=(_Float16)(v0.z*scale); hv[3]=(_Float16)(v0.w*scale);
    hv[4]=(_Float16)(v1.x*scale); hv[5]=(_Float16)(v1.y*scale);
    hv[6]=(_Float16)(v1.z*scale); hv[7]=(_Float16)(v1.w*scale);
    *(h16x8*)&dst[i8] = hv;
}

// fused setup: pack x fp16 linear (blocks 0..4095), pack e fp16*1024 linear
// (+0..127), esq (+128..383), keys init (+384..511), counts zero (+512).
// e pre-scaled by 2^10 (exact pow2; keeps fp16 normal); undone exactly in
// scores' fp32 epilogue (acc/512).
__global__ __launch_bounds__(256) void vq_setup(const float* __restrict__ x,
                                                const float* __restrict__ emb,
                                                u16* __restrict__ xh,
                                                u16* __restrict__ eh,
                                                float* __restrict__ esq,
                                                u64* __restrict__ keys,
                                                int* __restrict__ cnti) {
    const int b = blockIdx.x, tid = threadIdx.x;
    if (b < 4096) {                       // x: 4096*2048 = 8.39M elems
        pack8_lin(x, xh, (size_t)b * 2048 + tid * 8, 1.0f);
        return;
    }
    const int p = b - 4096;
    const int lane = tid & 63, w = tid >> 6;
    if (p < 128) {                        // e: 128*2048 = 262144 elems
        pack8_lin(emb, eh, (size_t)p * 2048 + tid * 8, 1024.0f);
    } else if (p < 384) {
        int c = (p - 128) * 4 + w;
        float4 v = *(const float4*)&emb[c * DIM + lane * 4];
        float s = v.x * v.x + v.y * v.y + v.z * v.z + v.w * v.w;
#pragma unroll
        for (int off = 32; off; off >>= 1) s += __shfl_xor(s, off, 64);
        if (lane == 0) esq[c] = s;
    } else if (p < 512) {
        keys[(p - 384) * 256 + tid] = ~0ULL;
    } else {
#pragma unroll
        for (int i = 0; i < 4; ++i) cnti[i * 256 + tid] = 0;
    }
}

// main MFMA scores+argmin: 2048 blocks; XCD swizzle. block = 128x128,
// 4 waves 2x2, wave = 4x4 grid of 16x16x32 fp16 MFMA (R3-proven numerics:
// dist = esq - acc/512).
//
// R6: ZERO-LDS main loop. R5 counters proved the LDS-staged 2-barrier
// structure is stall-bound (MfmaUtil 13.7%, 8 chunks x vmcnt(0)-drain+barrier
// dominate; K=256 too short for any staged pipeline to reach steady state).
// Every fragment here is consumed by exactly ONE wave, so LDS bought nothing:
// load A/B fragments global->register (16B/lane, offset-immediate kc stepping)
// and let the compiler's per-wave vmcnt scheduling hide L2 latency with ILP.
// No barriers until the epilogue. B-frags re-fetched per wave-pair but
// L2-resident (e-slice 64KB hot). Values/MFMA order bit-identical to R5.
__global__ __launch_bounds__(256) void vq_scores_mfma(const u16* __restrict__ xh,
                                                      const u16* __restrict__ eh,
                                                      const float* __restrict__ esq,
                                                      u64* __restrict__ keys) {
    __shared__ __align__(16) char smem[33792];   // epilogue argmin scratch only
    const int tid  = threadIdx.x;
    const int lane = tid & 63, w = tid >> 6;
    const int wm = w & 1, wn = w >> 1;
    const int raw = blockIdx.x;
    const int rb = (raw >> 6) * 8 + (raw & 7);
    const int cs = (raw >> 3) & 7;
    const int ln16 = lane & 15, q4 = lane >> 4;

    // per-lane fragment base pointers: frag (t, kc) lives at
    // base[t] + kc*32 elems (64B) — constant-offset loads inside the loop.
    const u16* ab[4];
    const u16* bb[4];
#pragma unroll
    for (int t = 0; t < 4; ++t) {
        int arow = rb * 128 + wm * 64 + t * 16 + ln16;
        ab[t] = xh + (size_t)arow * DIM + q4 * 8;
        int bcol = cs * 128 + wn * 64 + t * 16 + ln16;
        bb[t] = eh + (size_t)bcol * DIM + q4 * 8;
    }

    f32x4 acc[4][4];
#pragma unroll
    for (int i = 0; i < 4; ++i)
#pragma unroll
        for (int j = 0; j < 4; ++j) acc[i][j] = (f32x4)0.f;

#pragma unroll
    for (int kc = 0; kc < 8; ++kc) {
        h16x8 ah[4], bh[4];
#pragma unroll
        for (int t = 0; t < 4; ++t) {
            ah[t] = *(const h16x8*)(ab[t] + kc * 32);
            bh[t] = *(const h16x8*)(bb[t] + kc * 32);
        }
#pragma unroll
        for (int tn = 0; tn < 4; ++tn)
#pragma unroll
            for (int tm = 0; tm < 4; ++tm)
                acc[tm][tn] = __builtin_amdgcn_mfma_f32_16x16x32_f16(ah[tm], bh[tn], acc[tm][tn], 0, 0, 0);
    }

    // epilogue: dist = esq - acc/512, per-row argmin.
    // C/D layout: col = lane&15, row = (lane>>4)*4 + reg (m89/m91-verified)
    __syncthreads();
    float* cv = (float*)smem;            // [128 rows][33 slots] pad -> conflict-free
    int*   ci = (int*)(smem + 16896);
#pragma unroll
    for (int tm = 0; tm < 4; ++tm) {
        float bv[4];
        int   bi[4];
#pragma unroll
        for (int r = 0; r < 4; ++r) { bv[r] = FLT_MAX; bi[r] = 0; }
#pragma unroll
        for (int tn = 0; tn < 4; ++tn) {          // ascending col -> lowest-idx ties
            int c = cs * 128 + wn * 64 + tn * 16 + ln16;
            float ec = esq[c];
#pragma unroll
            for (int r = 0; r < 4; ++r) {
                float d = fmaf(-0.001953125f, acc[tm][tn][r], ec);
                if (d < bv[r]) { bv[r] = d; bi[r] = c; }
            }
        }
        int row0 = wm * 64 + tm * 16 + q4 * 4;
        int slot = wn * 16 + ln16;
#pragma unroll
        for (int r = 0; r < 4; ++r) {
            cv[(row0 + r) * 33 + slot] = bv[r];
            ci[(row0 + r) * 33 + slot] = bi[r];
        }
    }
    __syncthreads();
    if (tid < 128) {
        float bv = cv[tid * 33];
        int   bi = ci[tid * 33];
#pragma unroll
        for (int s = 1; s < 32; ++s) {
            float v = cv[tid * 33 + s];
            int  ix = ci[tid * 33 + s];
            if (v < bv || (v == bv && ix < bi)) { bv = v; bi = ix; }
        }
        u64 key = ((u64)fmap(bv) << 32) | (unsigned)bi;
        atomicMin(&keys[rb * 128 + tid], key);
    }
}

// streaming quantize + straight-through + loss partials + histogram + bi array.
// 2048 blocks x 16 rows; float4 throughout; one int atomic per row. (R4-proven;
// R4-fusion-into-mega measured 89us latency-bound — keep the split.)
__global__ __launch_bounds__(256) void vq_quant(const float* __restrict__ x,
                                                const float* __restrict__ emb,
                                                const u64* __restrict__ keys,
                                                float* __restrict__ outq,
                                                int* __restrict__ cnti,
                                                int* __restrict__ bi_arr,
                                                float* __restrict__ lpart) {
    const int tid = threadIdx.x, lane = tid & 63, w = tid >> 6;
    const float4* x4 = (const float4*)x;
    const float4* e4 = (const float4*)emb;
    float4* o4 = (float4*)outq;
    float lacc = 0.f;
#pragma unroll
    for (int it = 0; it < 4; ++it) {
        int row = blockIdx.x * 16 + it * 4 + w;
        int bi = (int)(unsigned)(keys[row] & 0xffffffffULL);
        if (lane == 0) { atomicAdd(&cnti[bi], 1); bi_arr[row] = bi; }
        float4 xv = x4[row * 64 + lane];
        float4 ev = e4[bi * 64 + lane];
        float4 q;
        q.x = xv.x + (ev.x - xv.x);  q.y = xv.y + (ev.y - xv.y);
        q.z = xv.z + (ev.z - xv.z);  q.w = xv.w + (ev.w - xv.w);
        o4[row * 64 + lane] = q;
        float dx = xv.x - ev.x, dy = xv.y - ev.y, dz = xv.z - ev.z, dwv = xv.w - ev.w;
        lacc += dx * dx + dy * dy + dz * dz + dwv * dwv;
    }
#pragma unroll
    for (int off = 32; off; off >>= 1) lacc += __shfl_xor(lacc, off, 64);
    __shared__ float red[4];
    if (lane == 0) red[w] = lacc;
    __syncthreads();
    if (tid == 0) lpart[blockIdx.x] = red[0] + red[1] + red[2] + red[3];
}

// mega-tail: grid 1024, one block per code m.
// int4 + unroll scan; n via the exact identity sum(counts) == N_TOK.
#define MEGA_CAP 6144
__global__ __launch_bounds__(256) void vq_mega(const float* __restrict__ x,
                                               const float* __restrict__ ema_count,
                                               const float* __restrict__ ema_weight,
                                               const int* __restrict__ cnti,
                                               const int* __restrict__ bi_arr,
                                               const float* __restrict__ lpart,
                                               float* __restrict__ out) {
    const int m = blockIdx.x, tid = threadIdx.x;
    __shared__ float fs[256];
    __shared__ int list[MEGA_CAP];
    __shared__ int lcount;

    float rsum = 0.f;
#pragma unroll
    for (int i = 0; i < 4; ++i) rsum += ema_count[tid * 4 + i];
    fs[tid] = rsum;
    if (tid == 0) lcount = 0;
    __syncthreads();
    for (int s = 128; s; s >>= 1) { if (tid < s) fs[tid] += fs[tid + s]; __syncthreads(); }
    const float n = DECAY_ * fs[0] + OMD_ * (float)N_TOK;
    __syncthreads();

    // scan bi_arr (int4, unrolled -> loads pipelined) for rows of code m
    const int4* b4 = (const int4*)bi_arr;
#pragma unroll 4
    for (int i = tid; i < N_TOK / 4; i += 256) {
        int4 v = b4[i];
        if (v.x == m) { int p = atomicAdd(&lcount, 1); if (p < MEGA_CAP) list[p] = 4 * i; }
        if (v.y == m) { int p = atomicAdd(&lcount, 1); if (p < MEGA_CAP) list[p] = 4 * i + 1; }
        if (v.z == m) { int p = atomicAdd(&lcount, 1); if (p < MEGA_CAP) list[p] = 4 * i + 2; }
        if (v.w == m) { int p = atomicAdd(&lcount, 1); if (p < MEGA_CAP) list[p] = 4 * i + 3; }
    }
    __syncthreads();
    const int nm = lcount;
    float dwsum;
    if (nm <= MEGA_CAP) {
        float a0 = 0.f, a1 = 0.f, a2 = 0.f, a3 = 0.f;
        int i = 0;
        for (; i + 4 <= nm; i += 4) {
            a0 += x[list[i]     * DIM + tid];
            a1 += x[list[i + 1] * DIM + tid];
            a2 += x[list[i + 2] * DIM + tid];
            a3 += x[list[i + 3] * DIM + tid];
        }
        for (; i < nm; ++i) a0 += x[list[i] * DIM + tid];
        dwsum = (a0 + a1) + (a2 + a3);
    } else {
        // defensive fallback (not expected with this data distribution)
        __shared__ int chunk[256];
        float a0 = 0.f;
        for (int base = 0; base < N_TOK; base += 256) {
            __syncthreads();
            chunk[tid] = bi_arr[base + tid];
            __syncthreads();
            for (int j = 0; j < 256; ++j)
                if (chunk[j] == m) a0 += x[(base + j) * DIM + tid];
        }
        dwsum = a0;
    }

    float raw_m = DECAY_ * ema_count[m] + OMD_ * (float)nm;
    float ncm = (raw_m + EPS_) / (n + MEPS_) * n;
    float nw = DECAY_ * ema_weight[m * DIM + tid] + OMD_ * dwsum;
    out[OUT_NW + m * DIM + tid] = nw;
    out[OUT_NE + m * DIM + tid] = nw / ncm;
    if (tid == 0) out[OUT_NC + m] = ncm;

    if (m == 0) {
        float ent = 0.f;
#pragma unroll
        for (int i = 0; i < 4; ++i) {
            float p = (float)cnti[tid * 4 + i] / (float)N_TOK;
            ent += p * logf(p + 1e-10f);
        }
        __syncthreads();
        fs[tid] = ent;
        __syncthreads();
        for (int s = 128; s; s >>= 1) { if (tid < s) fs[tid] += fs[tid + s]; __syncthreads(); }
        float entr = fs[0];
        __syncthreads();
        float ls = 0.f;
#pragma unroll
        for (int k = 0; k < 8; ++k) ls += lpart[tid + 256 * k];
        fs[tid] = ls;
        __syncthreads();
        for (int s = 128; s; s >>= 1) { if (tid < s) fs[tid] += fs[tid + s]; __syncthreads(); }
        if (tid == 0) {
            float mean = fs[0] / (float)(N_TOK * DIM);
            out[OUT_COMMIT]   = 0.25f * mean;
            out[OUT_CODEBOOK] = mean;
            out[OUT_PERP]     = expf(-entr);
        }
    }
}

extern "C" void kernel_launch(void* const* d_in, const int* in_sizes, int n_in,
                              void* d_out, int out_size, void* d_ws, size_t ws_size,
                              hipStream_t stream) {
    const float* x          = (const float*)d_in[0];
    const float* emb        = (const float*)d_in[1];
    const float* ema_count  = (const float*)d_in[2];
    const float* ema_weight = (const float*)d_in[3];
    float* out = (float*)d_out;
    float* wf  = (float*)d_ws;

    // xh lives in the d_out quantized region (16.8 of 33.5 MB); vq_quant
    // overwrites it afterwards.
    u16* xh = (u16*)d_out;
    u16* eh = (u16*)(wf + WS_EH);

    float* esq    = wf + WS_ESQ;
    int*   cnti   = (int*)(wf + WS_CNTI);
    int*   bi_arr = (int*)(wf + WS_BI);
    float* lpart  = wf + WS_LP;
    u64*   keys   = (u64*)(wf + WS_KEY);

    vq_setup<<<4609, 256, 0, stream>>>(x, emb, xh, eh, esq, keys, cnti);
    vq_scores_mfma<<<2048, 256, 0, stream>>>(xh, eh, esq, keys);
    vq_quant<<<2048, 256, 0, stream>>>(x, emb, keys, out, cnti, bi_arr, lpart);
    vq_mega<<<MCODE, 256, 0, stream>>>(x, ema_count, ema_weight, cnti, bi_arr,
                                       lpart, out);
}

// Round 7
// 149.608 us; speedup vs baseline: 1.2520x; 1.2520x over previous
//
#include <hip/hip_runtime.h>
#include <cfloat>
#include <math.h>

#define N_TOK 32768
#define DIM   256
#define MCODE 1024

typedef unsigned short u16;
typedef unsigned long long u64;
typedef __attribute__((ext_vector_type(8))) _Float16 h16x8;
typedef __attribute__((ext_vector_type(4))) float f32x4;

constexpr float DECAY_ = 0.999f;
constexpr float OMD_   = (float)(1.0 - 0.999);   // match jax double->f32 promotion
constexpr float EPS_   = 1e-5f;
constexpr float MEPS_  = (float)(1024 * 1e-5);   // M * EPS in double, then f32

// ---- workspace layout (float offsets) ----
// MUST stay <= 3,284,992 B (Round-1-proven ws_size bound).
constexpr int WS_EH   = 0;        // eh[1024*256] fp16 (fragment order) -> 131072 floats
constexpr int WS_ESQ  = 262144;   // esq[1024]
constexpr int WS_CNTI = 263168;   // int counts[1024] (zeroed in setup)
constexpr int WS_BI   = 264192;   // int bi[32768]
constexpr int WS_LP   = 296960;   // loss partials[2048]
constexpr int WS_KEY  = 299008;   // u64 keys[32768] (8B-aligned)

// ---- output layout (float offsets) ----
constexpr int OUT_Q        = 0;
constexpr int OUT_COMMIT   = 8388608;
constexpr int OUT_CODEBOOK = 8388609;
constexpr int OUT_PERP     = 8388610;
constexpr int OUT_NE       = 8388611;
constexpr int OUT_NC       = 8650755;
constexpr int OUT_NW       = 8651779;

static __device__ __forceinline__ void gl2lds16(const u16* g, char* l) {
    __builtin_amdgcn_global_load_lds(
        (const __attribute__((address_space(1))) unsigned int*)g,
        (__attribute__((address_space(3))) unsigned int*)l, 16, 0, 0);
}
// monotone float->uint map: a<b  <=>  map(a)<map(b)  (finite floats)
static __device__ __forceinline__ unsigned fmap(float f) {
    unsigned u = __float_as_uint(f);
    return (u & 0x80000000u) ? ~u : (u | 0x80000000u);
}

// MFMA-fragment global order (R3-proven; staging loads are 1KB/wave linear):
// dst[wave*512 + lane*8 + j] <-> src[row=(wave>>6)*128+(wave&7)*16+(lane&15)]
//                                   [k=((wave>>3)&7)*32+(lane>>4)*8+j]
static __device__ __forceinline__ void load_row8(const float* __restrict__ src,
                                                 int wave_id, int lane,
                                                 float* vv, size_t* o) {
    int rb = wave_id >> 6, kc = (wave_id >> 3) & 7, t = wave_id & 7;
    int row = rb * 128 + t * 16 + (lane & 15);
    int k   = kc * 32 + (lane >> 4) * 8;
    const float* s = &src[row * DIM + k];
    float4 v0 = *(const float4*)s, v1 = *(const float4*)(s + 4);
    vv[0]=v0.x; vv[1]=v0.y; vv[2]=v0.z; vv[3]=v0.w;
    vv[4]=v1.x; vv[5]=v1.y; vv[6]=v1.z; vv[7]=v1.w;
    *o = (size_t)wave_id * 512 + lane * 8;
}
// fp16 pack (RN-even). e pre-scaled by 1024 (exact pow2, keeps fp16 normal);
// undone exactly in scores' fp32 epilogue (acc/512).
static __device__ __forceinline__ void pack_wave_h16(const float* __restrict__ src,
                                                     u16* __restrict__ dst,
                                                     int wave_id, int lane,
                                                     float scale) {
    float vv[8]; size_t o;
    load_row8(src, wave_id, lane, vv, &o);
    h16x8 hv;
#pragma unroll
    for (int j = 0; j < 8; ++j) hv[j] = (_Float16)(vv[j] * scale);
    *(h16x8*)&dst[o] = hv;
}

// fused setup: pack x fp16 (blocks 0..4095), pack e fp16*1024 (+0..127),
// esq (+128..383), keys init (+384..511), counts zero (+512). (exact R3)
__global__ __launch_bounds__(256) void vq_setup(const float* __restrict__ x,
                                                const float* __restrict__ emb,
                                                u16* __restrict__ xh,
                                                u16* __restrict__ eh,
                                                float* __restrict__ esq,
                                                u64* __restrict__ keys,
                                                int* __restrict__ cnti) {
    const int b = blockIdx.x, tid = threadIdx.x;
    const int lane = tid & 63, w = tid >> 6;
    if (b < 4096) { pack_wave_h16(x, xh, b * 4 + w, lane, 1.0f); return; }
    const int p = b - 4096;
    if (p < 128) {
        pack_wave_h16(emb, eh, p * 4 + w, lane, 1024.0f);
    } else if (p < 384) {
        int c = (p - 128) * 4 + w;
        float4 v = *(const float4*)&emb[c * DIM + lane * 4];
        float s = v.x * v.x + v.y * v.y + v.z * v.z + v.w * v.w;
#pragma unroll
        for (int off = 32; off; off >>= 1) s += __shfl_xor(s, off, 64);
        if (lane == 0) esq[c] = s;
    } else if (p < 512) {
        keys[(p - 384) * 256 + tid] = ~0ULL;
    } else {
#pragma unroll
        for (int i = 0; i < 4; ++i) cnti[i * 256 + tid] = 0;
    }
}

// main MFMA scores+argmin: 2048 blocks; XCD swizzle. block = 128x128,
// 4 waves 2x2, wave = 4x4 grid of 16x16x32 fp16 MFMA. dist = esq - acc/512.
//
// R7: exact R3 structure (fragment-order sources, coalesced 1KB/wave glds,
// 2-syncthreads template) with BK doubled 32->64: stage TWO k-chunks (32KB)
// per phase -> 4 drain-barrier phases instead of 8. R5 counters showed the
// per-phase drain (not BW, not MFMA) dominates; R6 proved uncoalesced
// register loads are worse. MFMA accumulation order is bit-identical to R3
// (kc pairs run sequentially). LDS 33792 unchanged -> same occupancy.
__global__ __launch_bounds__(256) void vq_scores_mfma(const u16* __restrict__ xh,
                                                      const u16* __restrict__ eh,
                                                      const float* __restrict__ esq,
                                                      u64* __restrict__ keys) {
    __shared__ __align__(16) char smem[33792];
    const int tid  = threadIdx.x;
    const int lane = tid & 63, w = tid >> 6;
    const int wm = w & 1, wn = w >> 1;
    const int raw = blockIdx.x;
    const int rb = (raw >> 6) * 8 + (raw & 7);
    const int cs = (raw >> 3) & 7;

    const u16* gb0 = xh + (size_t)rb * 32768;
    const u16* gb1 = eh + (size_t)cs * 32768;

    f32x4 acc[4][4];
#pragma unroll
    for (int i = 0; i < 4; ++i)
#pragma unroll
        for (int j = 0; j < 4; ++j) acc[i][j] = (f32x4)0.f;

    for (int ph = 0; ph < 4; ++ph) {
        __syncthreads();   // previous phase's frag reads done before overwrite
        // 32 x 1KB wave-loads per phase (2 chunks); wave w takes [8w, 8w+8).
        // layout: half 0 -> {A@0, B@8K}, half 1 -> {A@16K, B@24K}
#pragma unroll
        for (int j = 0; j < 8; ++j) {
            int t = w * 8 + j;
            int half = t >> 4, tt = t & 15;
            int arr = tt >> 3, slot = tt & 7;
            const u16* g = (arr == 0 ? gb0 : gb1)
                           + (2 * ph + half) * 4096 + slot * 512 + lane * 8;
            gl2lds16(g, smem + half * 16384 + arr * 8192 + slot * 1024);
        }
        __syncthreads();   // drains vmcnt (incl. global_load_lds) + barrier

#pragma unroll
        for (int half = 0; half < 2; ++half) {
            const h16x8* Ah = (const h16x8*)(smem + half * 16384);
            const h16x8* Bh = (const h16x8*)(smem + half * 16384 + 8192);
            h16x8 ah[4];
#pragma unroll
            for (int tm = 0; tm < 4; ++tm)
                ah[tm] = Ah[(wm * 4 + tm) * 64 + lane];
#pragma unroll
            for (int tn = 0; tn < 4; ++tn) {
                h16x8 bh = Bh[(wn * 4 + tn) * 64 + lane];
#pragma unroll
                for (int tm = 0; tm < 4; ++tm) {
                    acc[tm][tn] = __builtin_amdgcn_mfma_f32_16x16x32_f16(ah[tm], bh, acc[tm][tn], 0, 0, 0);
                }
            }
        }
    }

    // epilogue: dist = esq - acc/512, per-row argmin. (exact R3)
    // C/D layout: col = lane&15, row = (lane>>4)*4 + reg (m89/m91-verified)
    __syncthreads();
    float* cv = (float*)smem;            // [128 rows][33 slots] pad -> conflict-free
    int*   ci = (int*)(smem + 16896);
    const int ln = lane & 15, quad = lane >> 4;
#pragma unroll
    for (int tm = 0; tm < 4; ++tm) {
        float bv[4];
        int   bi[4];
#pragma unroll
        for (int r = 0; r < 4; ++r) { bv[r] = FLT_MAX; bi[r] = 0; }
#pragma unroll
        for (int tn = 0; tn < 4; ++tn) {          // ascending col -> lowest-idx ties
            int c = cs * 128 + wn * 64 + tn * 16 + ln;
            float ec = esq[c];
#pragma unroll
            for (int r = 0; r < 4; ++r) {
                float d = fmaf(-0.001953125f, acc[tm][tn][r], ec);
                if (d < bv[r]) { bv[r] = d; bi[r] = c; }
            }
        }
        int row0 = wm * 64 + tm * 16 + quad * 4;
        int slot = wn * 16 + ln;
#pragma unroll
        for (int r = 0; r < 4; ++r) {
            cv[(row0 + r) * 33 + slot] = bv[r];
            ci[(row0 + r) * 33 + slot] = bi[r];
        }
    }
    __syncthreads();
    if (tid < 128) {
        float bv = cv[tid * 33];
        int   bi = ci[tid * 33];
#pragma unroll
        for (int s = 1; s < 32; ++s) {
            float v = cv[tid * 33 + s];
            int  ix = ci[tid * 33 + s];
            if (v < bv || (v == bv && ix < bi)) { bv = v; bi = ix; }
        }
        u64 key = ((u64)fmap(bv) << 32) | (unsigned)bi;
        atomicMin(&keys[rb * 128 + tid], key);
    }
}

// streaming quantize + straight-through + loss partials + histogram + bi array.
// 2048 blocks x 16 rows; float4 throughout; one int atomic per row. (R4-proven;
// fusion-into-mega measured 89us latency-bound — keep the split.)
__global__ __launch_bounds__(256) void vq_quant(const float* __restrict__ x,
                                                const float* __restrict__ emb,
                                                const u64* __restrict__ keys,
                                                float* __restrict__ outq,
                                                int* __restrict__ cnti,
                                                int* __restrict__ bi_arr,
                                                float* __restrict__ lpart) {
    const int tid = threadIdx.x, lane = tid & 63, w = tid >> 6;
    const float4* x4 = (const float4*)x;
    const float4* e4 = (const float4*)emb;
    float4* o4 = (float4*)outq;
    float lacc = 0.f;
#pragma unroll
    for (int it = 0; it < 4; ++it) {
        int row = blockIdx.x * 16 + it * 4 + w;
        int bi = (int)(unsigned)(keys[row] & 0xffffffffULL);
        if (lane == 0) { atomicAdd(&cnti[bi], 1); bi_arr[row] = bi; }
        float4 xv = x4[row * 64 + lane];
        float4 ev = e4[bi * 64 + lane];
        float4 q;
        q.x = xv.x + (ev.x - xv.x);  q.y = xv.y + (ev.y - xv.y);
        q.z = xv.z + (ev.z - xv.z);  q.w = xv.w + (ev.w - xv.w);
        o4[row * 64 + lane] = q;
        float dx = xv.x - ev.x, dy = xv.y - ev.y, dz = xv.z - ev.z, dwv = xv.w - ev.w;
        lacc += dx * dx + dy * dy + dz * dz + dwv * dwv;
    }
#pragma unroll
    for (int off = 32; off; off >>= 1) lacc += __shfl_xor(lacc, off, 64);
    __shared__ float red[4];
    if (lane == 0) red[w] = lacc;
    __syncthreads();
    if (tid == 0) lpart[blockIdx.x] = red[0] + red[1] + red[2] + red[3];
}

// mega-tail: grid 1024, one block per code m.
// int4 + unroll scan; n via the exact identity sum(counts) == N_TOK.
#define MEGA_CAP 6144
__global__ __launch_bounds__(256) void vq_mega(const float* __restrict__ x,
                                               const float* __restrict__ ema_count,
                                               const float* __restrict__ ema_weight,
                                               const int* __restrict__ cnti,
                                               const int* __restrict__ bi_arr,
                                               const float* __restrict__ lpart,
                                               float* __restrict__ out) {
    const int m = blockIdx.x, tid = threadIdx.x;
    __shared__ float fs[256];
    __shared__ int list[MEGA_CAP];
    __shared__ int lcount;

    float rsum = 0.f;
#pragma unroll
    for (int i = 0; i < 4; ++i) rsum += ema_count[tid * 4 + i];
    fs[tid] = rsum;
    if (tid == 0) lcount = 0;
    __syncthreads();
    for (int s = 128; s; s >>= 1) { if (tid < s) fs[tid] += fs[tid + s]; __syncthreads(); }
    const float n = DECAY_ * fs[0] + OMD_ * (float)N_TOK;
    __syncthreads();

    // scan bi_arr (int4, unrolled -> loads pipelined) for rows of code m
    const int4* b4 = (const int4*)bi_arr;
#pragma unroll 4
    for (int i = tid; i < N_TOK / 4; i += 256) {
        int4 v = b4[i];
        if (v.x == m) { int p = atomicAdd(&lcount, 1); if (p < MEGA_CAP) list[p] = 4 * i; }
        if (v.y == m) { int p = atomicAdd(&lcount, 1); if (p < MEGA_CAP) list[p] = 4 * i + 1; }
        if (v.z == m) { int p = atomicAdd(&lcount, 1); if (p < MEGA_CAP) list[p] = 4 * i + 2; }
        if (v.w == m) { int p = atomicAdd(&lcount, 1); if (p < MEGA_CAP) list[p] = 4 * i + 3; }
    }
    __syncthreads();
    const int nm = lcount;
    float dwsum;
    if (nm <= MEGA_CAP) {
        float a0 = 0.f, a1 = 0.f, a2 = 0.f, a3 = 0.f;
        int i = 0;
        for (; i + 4 <= nm; i += 4) {
            a0 += x[list[i]     * DIM + tid];
            a1 += x[list[i + 1] * DIM + tid];
            a2 += x[list[i + 2] * DIM + tid];
            a3 += x[list[i + 3] * DIM + tid];
        }
        for (; i < nm; ++i) a0 += x[list[i] * DIM + tid];
        dwsum = (a0 + a1) + (a2 + a3);
    } else {
        // defensive fallback (not expected with this data distribution)
        __shared__ int chunk[256];
        float a0 = 0.f;
        for (int base = 0; base < N_TOK; base += 256) {
            __syncthreads();
            chunk[tid] = bi_arr[base + tid];
            __syncthreads();
            for (int j = 0; j < 256; ++j)
                if (chunk[j] == m) a0 += x[(base + j) * DIM + tid];
        }
        dwsum = a0;
    }

    float raw_m = DECAY_ * ema_count[m] + OMD_ * (float)nm;
    float ncm = (raw_m + EPS_) / (n + MEPS_) * n;
    float nw = DECAY_ * ema_weight[m * DIM + tid] + OMD_ * dwsum;
    out[OUT_NW + m * DIM + tid] = nw;
    out[OUT_NE + m * DIM + tid] = nw / ncm;
    if (tid == 0) out[OUT_NC + m] = ncm;

    if (m == 0) {
        float ent = 0.f;
#pragma unroll
        for (int i = 0; i < 4; ++i) {
            float p = (float)cnti[tid * 4 + i] / (float)N_TOK;
            ent += p * logf(p + 1e-10f);
        }
        __syncthreads();
        fs[tid] = ent;
        __syncthreads();
        for (int s = 128; s; s >>= 1) { if (tid < s) fs[tid] += fs[tid + s]; __syncthreads(); }
        float entr = fs[0];
        __syncthreads();
        float ls = 0.f;
#pragma unroll
        for (int k = 0; k < 8; ++k) ls += lpart[tid + 256 * k];
        fs[tid] = ls;
        __syncthreads();
        for (int s = 128; s; s >>= 1) { if (tid < s) fs[tid] += fs[tid + s]; __syncthreads(); }
        if (tid == 0) {
            float mean = fs[0] / (float)(N_TOK * DIM);
            out[OUT_COMMIT]   = 0.25f * mean;
            out[OUT_CODEBOOK] = mean;
            out[OUT_PERP]     = expf(-entr);
        }
    }
}

extern "C" void kernel_launch(void* const* d_in, const int* in_sizes, int n_in,
                              void* d_out, int out_size, void* d_ws, size_t ws_size,
                              hipStream_t stream) {
    const float* x          = (const float*)d_in[0];
    const float* emb        = (const float*)d_in[1];
    const float* ema_count  = (const float*)d_in[2];
    const float* ema_weight = (const float*)d_in[3];
    float* out = (float*)d_out;
    float* wf  = (float*)d_ws;

    // xh lives in the d_out quantized region (16.8 of 33.5 MB); vq_quant
    // overwrites it afterwards.
    u16* xh = (u16*)d_out;
    u16* eh = (u16*)(wf + WS_EH);

    float* esq    = wf + WS_ESQ;
    int*   cnti   = (int*)(wf + WS_CNTI);
    int*   bi_arr = (int*)(wf + WS_BI);
    float* lpart  = wf + WS_LP;
    u64*   keys   = (u64*)(wf + WS_KEY);

    vq_setup<<<4609, 256, 0, stream>>>(x, emb, xh, eh, esq, keys, cnti);
    vq_scores_mfma<<<2048, 256, 0, stream>>>(xh, eh, esq, keys);
    vq_quant<<<2048, 256, 0, stream>>>(x, emb, keys, out, cnti, bi_arr, lpart);
    vq_mega<<<MCODE, 256, 0, stream>>>(x, ema_count, ema_weight, cnti, bi_arr,
                                       lpart, out);
}